// Round 1
// baseline (10511.967 us; speedup 1.0000x reference)
//
#include <hip/hip_runtime.h>
#include <math.h>

#define H 16
#define NF 64
#define TPB 256

__device__ __forceinline__ float lrelu(float v){ return v > 0.f ? v : 0.2f*v; }

// ---- derived edge-attention weights: w = We @ a_e (2 floats per layer) ----
__global__ void k_prep(const float* __restrict__ We1, const float* __restrict__ ae1,
                       const float* __restrict__ We2, const float* __restrict__ ae2,
                       float* __restrict__ params){
  int t = threadIdx.x;
  if (t < 4){
    const float* We = (t < 2) ? We1 : We2;
    const float* ae = (t < 2) ? ae1 : ae2;
    int r = t & 1;
    float s = 0.f;
    for (int c = 0; c < H; ++c) s += We[r*H + c] * ae[c];
    params[t] = s;
  }
}

// ---- degree + segment-sum of edge_attr over dst (once, reused by both layers) ----
__global__ __launch_bounds__(TPB) void k_deg(const int* __restrict__ dst, const float* __restrict__ attr,
                      float* __restrict__ cnt, float* __restrict__ sum_attr, int E){
  int e = blockIdx.x*TPB + threadIdx.x;
  if (e >= E) return;
  int d = dst[e];
  float2 a = ((const float2*)attr)[e];
  atomicAdd(&cnt[d], 1.f);
  atomicAdd(&sum_attr[2*d+0], a.x);
  atomicAdd(&sum_attr[2*d+1], a.y);
}

// ---- layer-1 node transform: h = x @ W1, alpha_src/dst, self-loop alpha_e ----
__global__ __launch_bounds__(TPB) void k_node1(const float* __restrict__ x, const float* __restrict__ W,
    const float* __restrict__ av_s, const float* __restrict__ av_d,
    const float* __restrict__ wp, const float* __restrict__ cnt, const float* __restrict__ sat,
    float* __restrict__ hout, float* __restrict__ asn, float* __restrict__ adn,
    float* __restrict__ lae, int N){
  __shared__ float sW[NF*H];
  __shared__ float sas[H], sad[H];
  int t = threadIdx.x;
  for (int i = t; i < NF*H; i += TPB) sW[i] = W[i];
  if (t < H){ sas[t] = av_s[t]; sad[t] = av_d[t]; }
  __syncthreads();
  int n = blockIdx.x*TPB + t;
  if (n >= N) return;
  float h[H];
  #pragma unroll
  for (int j = 0; j < H; ++j) h[j] = 0.f;
  const float4* xr = (const float4*)(x + (size_t)n*NF);
  #pragma unroll
  for (int k4 = 0; k4 < NF/4; ++k4){
    float4 xv = xr[k4];
    #pragma unroll
    for (int j = 0; j < H; ++j){
      h[j] += xv.x*sW[(4*k4+0)*H+j] + xv.y*sW[(4*k4+1)*H+j]
            + xv.z*sW[(4*k4+2)*H+j] + xv.w*sW[(4*k4+3)*H+j];
    }
  }
  float4* ho = (float4*)(hout + (size_t)n*H);
  ho[0] = make_float4(h[0],h[1],h[2],h[3]);
  ho[1] = make_float4(h[4],h[5],h[6],h[7]);
  ho[2] = make_float4(h[8],h[9],h[10],h[11]);
  ho[3] = make_float4(h[12],h[13],h[14],h[15]);
  float ss = 0.f, sd = 0.f;
  #pragma unroll
  for (int j = 0; j < H; ++j){ ss += h[j]*sas[j]; sd += h[j]*sad[j]; }
  asn[n] = ss; adn[n] = sd;
  float2 sa = ((const float2*)sat)[n];
  lae[n] = (sa.x*wp[0] + sa.y*wp[1]) / fmaxf(cnt[n], 1.f);
}

// ---- softmax denominator (no max-subtraction; logits are O(1)) ----
__global__ __launch_bounds__(TPB) void k_den(const int* __restrict__ src, const int* __restrict__ dst,
    const float* __restrict__ attr, const float* __restrict__ asn, const float* __restrict__ adn,
    const float* __restrict__ lae, const float* __restrict__ wp, float* __restrict__ den,
    int E, int N){
  int i = blockIdx.x*TPB + threadIdx.x;
  float v; int d;
  if (i < E){
    int s = src[i]; d = dst[i];
    float2 a = ((const float2*)attr)[i];
    v = asn[s] + adn[d] + a.x*wp[0] + a.y*wp[1];
  } else if (i < E + N){
    int n = i - E; d = n;
    v = asn[n] + adn[n] + lae[n];
  } else return;
  atomicAdd(&den[d], __expf(lrelu(v)));
}

// ---- weighted scatter: out[dst] += alpha * h[src] ----
__global__ __launch_bounds__(TPB) void k_acc(const int* __restrict__ src, const int* __restrict__ dst,
    const float* __restrict__ attr, const float* __restrict__ asn, const float* __restrict__ adn,
    const float* __restrict__ lae, const float* __restrict__ wp, const float* __restrict__ den,
    const float* __restrict__ h, float* __restrict__ out, int E, int N){
  int i = blockIdx.x*TPB + threadIdx.x;
  int s, d; float v;
  if (i < E){
    s = src[i]; d = dst[i];
    float2 a = ((const float2*)attr)[i];
    v = asn[s] + adn[d] + a.x*wp[0] + a.y*wp[1];
  } else if (i < E + N){
    s = d = i - E;
    v = asn[s] + adn[s] + lae[s];
  } else return;
  float alpha = __expf(lrelu(v)) / (den[d] + 1e-16f);
  const float4* hr = (const float4*)(h + (size_t)s*H);
  float4 h0 = hr[0], h1 = hr[1], h2 = hr[2], h3 = hr[3];
  float* o = out + (size_t)d*H;
  atomicAdd(&o[0],  alpha*h0.x); atomicAdd(&o[1],  alpha*h0.y);
  atomicAdd(&o[2],  alpha*h0.z); atomicAdd(&o[3],  alpha*h0.w);
  atomicAdd(&o[4],  alpha*h1.x); atomicAdd(&o[5],  alpha*h1.y);
  atomicAdd(&o[6],  alpha*h1.z); atomicAdd(&o[7],  alpha*h1.w);
  atomicAdd(&o[8],  alpha*h2.x); atomicAdd(&o[9],  alpha*h2.y);
  atomicAdd(&o[10], alpha*h2.z); atomicAdd(&o[11], alpha*h2.w);
  atomicAdd(&o[12], alpha*h3.x); atomicAdd(&o[13], alpha*h3.y);
  atomicAdd(&o[14], alpha*h3.z); atomicAdd(&o[15], alpha*h3.w);
}

// ---- bias + relu in place, accumulate BN sum/sumsq via wave reduction ----
__global__ __launch_bounds__(TPB) void k_postact(float* __restrict__ B, const float* __restrict__ bias,
    float* __restrict__ bnstats, int N){
  int t = threadIdx.x;
  int n = blockIdx.x*TPB + t;
  float v[H];
  if (n < N){
    float4* br = (float4*)(B + (size_t)n*H);
    float4 a0 = br[0], a1 = br[1], a2 = br[2], a3 = br[3];
    v[0]=a0.x; v[1]=a0.y; v[2]=a0.z; v[3]=a0.w;
    v[4]=a1.x; v[5]=a1.y; v[6]=a1.z; v[7]=a1.w;
    v[8]=a2.x; v[9]=a2.y; v[10]=a2.z; v[11]=a2.w;
    v[12]=a3.x; v[13]=a3.y; v[14]=a3.z; v[15]=a3.w;
    #pragma unroll
    for (int f = 0; f < H; ++f) v[f] = fmaxf(v[f] + bias[f], 0.f);
    br[0] = make_float4(v[0],v[1],v[2],v[3]);
    br[1] = make_float4(v[4],v[5],v[6],v[7]);
    br[2] = make_float4(v[8],v[9],v[10],v[11]);
    br[3] = make_float4(v[12],v[13],v[14],v[15]);
  } else {
    #pragma unroll
    for (int f = 0; f < H; ++f) v[f] = 0.f;
  }
  float s[H], q[H];
  #pragma unroll
  for (int f = 0; f < H; ++f){ s[f] = v[f]; q[f] = v[f]*v[f]; }
  for (int m = 1; m < 64; m <<= 1){
    #pragma unroll
    for (int f = 0; f < H; ++f){
      s[f] += __shfl_xor(s[f], m);
      q[f] += __shfl_xor(q[f], m);
    }
  }
  if ((t & 63) == 0){
    #pragma unroll
    for (int f = 0; f < H; ++f){
      atomicAdd(&bnstats[f], s[f]);
      atomicAdd(&bnstats[H+f], q[f]);
    }
  }
}

__global__ void k_bnprep(const float* __restrict__ bnstats, const float* __restrict__ gamma,
    const float* __restrict__ beta, float* __restrict__ scale, float* __restrict__ shift, int N){
  int f = threadIdx.x;
  if (f >= H) return;
  float inv = 1.f / (float)N;
  float mu  = bnstats[f] * inv;
  float var = bnstats[H+f] * inv - mu*mu;
  float sc  = gamma[f] * rsqrtf(var + 1e-5f);
  scale[f] = sc;
  shift[f] = beta[f] - mu*sc;
}

// ---- layer-2 node transform: apply BN, h = xn @ W2, alphas, self-loop alpha_e ----
__global__ __launch_bounds__(TPB) void k_node2(const float* __restrict__ Bin, const float* __restrict__ scale,
    const float* __restrict__ shift, const float* __restrict__ W,
    const float* __restrict__ av_s, const float* __restrict__ av_d, const float* __restrict__ wp,
    const float* __restrict__ cnt, const float* __restrict__ sat,
    float* __restrict__ hout, float* __restrict__ asn, float* __restrict__ adn,
    float* __restrict__ lae, int N){
  __shared__ float sW[H*H];
  __shared__ float ssc[H], ssh[H], sas[H], sad[H];
  int t = threadIdx.x;
  if (t < H*H) sW[t] = W[t];
  if (t < H){ ssc[t] = scale[t]; ssh[t] = shift[t]; sas[t] = av_s[t]; sad[t] = av_d[t]; }
  __syncthreads();
  int n = blockIdx.x*TPB + t;
  if (n >= N) return;
  const float4* br = (const float4*)(Bin + (size_t)n*H);
  float4 a0 = br[0], a1 = br[1], a2 = br[2], a3 = br[3];
  float xn[H] = {a0.x,a0.y,a0.z,a0.w, a1.x,a1.y,a1.z,a1.w,
                 a2.x,a2.y,a2.z,a2.w, a3.x,a3.y,a3.z,a3.w};
  #pragma unroll
  for (int f = 0; f < H; ++f) xn[f] = xn[f]*ssc[f] + ssh[f];
  float h[H];
  #pragma unroll
  for (int j = 0; j < H; ++j) h[j] = 0.f;
  #pragma unroll
  for (int k = 0; k < H; ++k){
    float xv = xn[k];
    #pragma unroll
    for (int j = 0; j < H; ++j) h[j] += xv * sW[k*H+j];
  }
  float4* ho = (float4*)(hout + (size_t)n*H);
  ho[0] = make_float4(h[0],h[1],h[2],h[3]);
  ho[1] = make_float4(h[4],h[5],h[6],h[7]);
  ho[2] = make_float4(h[8],h[9],h[10],h[11]);
  ho[3] = make_float4(h[12],h[13],h[14],h[15]);
  float ss = 0.f, sd = 0.f;
  #pragma unroll
  for (int j = 0; j < H; ++j){ ss += h[j]*sas[j]; sd += h[j]*sad[j]; }
  asn[n] = ss; adn[n] = sd;
  float2 sa = ((const float2*)sat)[n];
  lae[n] = (sa.x*wp[0] + sa.y*wp[1]) / fmaxf(cnt[n], 1.f);
}

// ---- bias + relu + mean-pool accumulation ----
__global__ __launch_bounds__(TPB) void k_pool(const float* __restrict__ B, const float* __restrict__ bias,
    const int* __restrict__ batch, float* __restrict__ pooled, float* __restrict__ gcnt, int N){
  int n = blockIdx.x*TPB + threadIdx.x;
  if (n >= N) return;
  int g = batch[n];
  const float4* br = (const float4*)(B + (size_t)n*H);
  float4 a0 = br[0], a1 = br[1], a2 = br[2], a3 = br[3];
  float v[H] = {a0.x,a0.y,a0.z,a0.w, a1.x,a1.y,a1.z,a1.w,
                a2.x,a2.y,a2.z,a2.w, a3.x,a3.y,a3.z,a3.w};
  float* p = pooled + (size_t)g*H;
  #pragma unroll
  for (int f = 0; f < H; ++f) atomicAdd(&p[f], fmaxf(v[f] + bias[f], 0.f));
  atomicAdd(&gcnt[g], 1.f);
}

// ---- D2RL head: one block of 512 threads (one per graph) ----
__device__ void block_stats16(const float* v, float* mu, float* rs,
                              float* wsum, float* wsq, int G){
  float s[H], q[H];
  #pragma unroll
  for (int f = 0; f < H; ++f){ s[f] = v[f]; q[f] = v[f]*v[f]; }
  for (int m = 1; m < 64; m <<= 1){
    #pragma unroll
    for (int f = 0; f < H; ++f){
      s[f] += __shfl_xor(s[f], m);
      q[f] += __shfl_xor(q[f], m);
    }
  }
  int wave = threadIdx.x >> 6, lane = threadIdx.x & 63;
  if (lane == 0){
    #pragma unroll
    for (int f = 0; f < H; ++f){ wsum[wave*H+f] = s[f]; wsq[wave*H+f] = q[f]; }
  }
  __syncthreads();
  int t = threadIdx.x;
  if (t < H){
    float S = 0.f, Q = 0.f;
    for (int w = 0; w < 8; ++w){ S += wsum[w*H+t]; Q += wsq[w*H+t]; }
    float m_ = S / (float)G;
    float var = Q / (float)G - m_*m_;
    mu[t] = m_;
    rs[t] = rsqrtf(var + 1e-5f);
  }
  __syncthreads();
}

__global__ __launch_bounds__(512) void k_head(const float* __restrict__ pooled, const float* __restrict__ gcnt,
    const float* __restrict__ g1, const float* __restrict__ be1,
    const float* __restrict__ Wl1, const float* __restrict__ bl1,
    const float* __restrict__ g2, const float* __restrict__ be2,
    const float* __restrict__ Wl2, const float* __restrict__ bl2,
    const float* __restrict__ g3, const float* __restrict__ be3,
    const float* __restrict__ Wl3, const float* __restrict__ bl3,
    const float* __restrict__ Wo, const float* __restrict__ bo,
    float* __restrict__ out, int G){
  __shared__ float wsum[8*H], wsq[8*H];
  __shared__ float pmu[H], prs[H], smu[H], srs[H];
  int g = threadIdx.x;
  float p[H];
  if (g < G){
    float c = fmaxf(gcnt[g], 1.f);
    #pragma unroll
    for (int f = 0; f < H; ++f) p[f] = pooled[(size_t)g*H+f] / c;
  } else {
    #pragma unroll
    for (int f = 0; f < H; ++f) p[f] = 0.f;
  }
  block_stats16(p, pmu, prs, wsum, wsq, G);
  // z1 = relu(bn(pooled) @ Wl1 + bl1)
  float xn[H], z[H];
  #pragma unroll
  for (int f = 0; f < H; ++f) xn[f] = g1[f]*(p[f]-pmu[f])*prs[f] + be1[f];
  #pragma unroll
  for (int j = 0; j < H; ++j) z[j] = bl1[j];
  for (int k = 0; k < H; ++k){
    float xv = xn[k];
    #pragma unroll
    for (int j = 0; j < H; ++j) z[j] += xv * Wl1[k*H+j];
  }
  #pragma unroll
  for (int j = 0; j < H; ++j) z[j] = fmaxf(z[j], 0.f);
  block_stats16(z, smu, srs, wsum, wsq, G);
  // z2 = relu(bn([z1, pooled]) @ Wl2 + bl2)
  float x2[2*H], z2[H];
  #pragma unroll
  for (int f = 0; f < H; ++f){
    x2[f]   = g2[f]  *(z[f]-smu[f])*srs[f] + be2[f];
    x2[H+f] = g2[H+f]*(p[f]-pmu[f])*prs[f] + be2[H+f];
  }
  #pragma unroll
  for (int j = 0; j < H; ++j) z2[j] = bl2[j];
  for (int k = 0; k < 2*H; ++k){
    float xv = x2[k];
    #pragma unroll
    for (int j = 0; j < H; ++j) z2[j] += xv * Wl2[k*H+j];
  }
  #pragma unroll
  for (int j = 0; j < H; ++j) z2[j] = fmaxf(z2[j], 0.f);
  block_stats16(z2, smu, srs, wsum, wsq, G);
  // z3 = relu(bn([z2, pooled]) @ Wl3 + bl3)
  float x3[2*H], z3[H];
  #pragma unroll
  for (int f = 0; f < H; ++f){
    x3[f]   = g3[f]  *(z2[f]-smu[f])*srs[f] + be3[f];
    x3[H+f] = g3[H+f]*(p[f]-pmu[f])*prs[f] + be3[H+f];
  }
  #pragma unroll
  for (int j = 0; j < H; ++j) z3[j] = bl3[j];
  for (int k = 0; k < 2*H; ++k){
    float xv = x3[k];
    #pragma unroll
    for (int j = 0; j < H; ++j) z3[j] += xv * Wl3[k*H+j];
  }
  #pragma unroll
  for (int j = 0; j < H; ++j) z3[j] = fmaxf(z3[j], 0.f);
  if (g < G){
    float o = bo[0];
    #pragma unroll
    for (int j = 0; j < H; ++j) o += z3[j]*Wo[j];
    out[g] = o;
  }
}

extern "C" void kernel_launch(void* const* d_in, const int* in_sizes, int n_in,
                              void* d_out, int out_size, void* d_ws, size_t ws_size,
                              hipStream_t stream) {
  const float* x     = (const float*)d_in[0];
  const int*   ei    = (const int*)d_in[1];
  const float* attr  = (const float*)d_in[2];
  const int*   batch = (const int*)d_in[3];
  const float* W1  = (const float*)d_in[4];
  const float* We1 = (const float*)d_in[5];
  const float* as1 = (const float*)d_in[6];
  const float* ad1 = (const float*)d_in[7];
  const float* ae1 = (const float*)d_in[8];
  const float* b1  = (const float*)d_in[9];
  const float* bn1g = (const float*)d_in[10];
  const float* bn1b = (const float*)d_in[11];
  const float* W2  = (const float*)d_in[12];
  const float* We2 = (const float*)d_in[13];
  const float* as2 = (const float*)d_in[14];
  const float* ad2 = (const float*)d_in[15];
  const float* ae2 = (const float*)d_in[16];
  const float* b2  = (const float*)d_in[17];
  const float* bnl1g = (const float*)d_in[18];
  const float* bnl1b = (const float*)d_in[19];
  const float* Wl1 = (const float*)d_in[20];
  const float* bl1 = (const float*)d_in[21];
  const float* bnl2g = (const float*)d_in[22];
  const float* bnl2b = (const float*)d_in[23];
  const float* Wl2 = (const float*)d_in[24];
  const float* bl2 = (const float*)d_in[25];
  const float* bnl3g = (const float*)d_in[26];
  const float* bnl3b = (const float*)d_in[27];
  const float* Wl3 = (const float*)d_in[28];
  const float* bl3 = (const float*)d_in[29];
  const float* Wo  = (const float*)d_in[30];
  const float* bo  = (const float*)d_in[31];

  int N = in_sizes[0] / NF;
  int E = in_sizes[1] / 2;
  int G = out_size;
  const int* srcp = ei;
  const int* dstp = ei + E;

  float* ws = (float*)d_ws;
  size_t off = 0;
  float* A   = ws + off; off += (size_t)16*N;   // h (current layer)
  float* Bv  = ws + off; off += (size_t)16*N;   // aggregation accumulator / layer output
  float* asn = ws + off; off += N;              // alpha_src per node
  float* adn = ws + off; off += N;              // alpha_dst per node
  float* lae = ws + off; off += N;              // self-loop alpha_e per node
  float* cnt = ws + off; off += N;              // in-degree          (zero region start)
  float* sat = ws + off; off += (size_t)2*N;    // sum of edge_attr over dst
  float* den = ws + off; off += N;              // softmax denominator (zero region end)
  float* par = ws + off; off += 128;            // [0..1]=w1 [2..3]=w2 [4..35]=bnstats [36..51]=scale [52..67]=shift
  float* pooled = ws + off; off += (size_t)G*H;
  float* gcnt   = ws + off; off += G;

  float* bnstats = par + 4;
  float* bnscale = par + 36;
  float* bnshift = par + 52;

  int nbE  = (E + TPB - 1)/TPB;
  int nbEN = (E + N + TPB - 1)/TPB;
  int nbN  = (N + TPB - 1)/TPB;

  // zero-init (ws is poisoned 0xAA before every launch)
  hipMemsetAsync(cnt, 0, (size_t)4*N*sizeof(float), stream);       // cnt + sat + den
  hipMemsetAsync(Bv, 0, (size_t)16*N*sizeof(float), stream);
  hipMemsetAsync(bnstats, 0, 32*sizeof(float), stream);
  hipMemsetAsync(pooled, 0, (size_t)(G*H + G)*sizeof(float), stream);

  k_prep<<<1, 64, 0, stream>>>(We1, ae1, We2, ae2, par);
  k_deg<<<nbE, TPB, 0, stream>>>(dstp, attr, cnt, sat, E);

  // ---- layer 1 ----
  k_node1<<<nbN, TPB, 0, stream>>>(x, W1, as1, ad1, par, cnt, sat, A, asn, adn, lae, N);
  k_den<<<nbEN, TPB, 0, stream>>>(srcp, dstp, attr, asn, adn, lae, par, den, E, N);
  k_acc<<<nbEN, TPB, 0, stream>>>(srcp, dstp, attr, asn, adn, lae, par, den, A, Bv, E, N);
  k_postact<<<nbN, TPB, 0, stream>>>(Bv, b1, bnstats, N);
  k_bnprep<<<1, 64, 0, stream>>>(bnstats, bn1g, bn1b, bnscale, bnshift, N);

  // ---- layer 2 ----
  k_node2<<<nbN, TPB, 0, stream>>>(Bv, bnscale, bnshift, W2, as2, ad2, par + 2, cnt, sat,
                                   A, asn, adn, lae, N);
  hipMemsetAsync(den, 0, (size_t)N*sizeof(float), stream);
  hipMemsetAsync(Bv, 0, (size_t)16*N*sizeof(float), stream);
  k_den<<<nbEN, TPB, 0, stream>>>(srcp, dstp, attr, asn, adn, lae, par + 2, den, E, N);
  k_acc<<<nbEN, TPB, 0, stream>>>(srcp, dstp, attr, asn, adn, lae, par + 2, den, A, Bv, E, N);

  // ---- pool + head ----
  k_pool<<<nbN, TPB, 0, stream>>>(Bv, b2, batch, pooled, gcnt, N);
  k_head<<<1, 512, 0, stream>>>(pooled, gcnt, bnl1g, bnl1b, Wl1, bl1, bnl2g, bnl2b, Wl2, bl2,
                                bnl3g, bnl3b, Wl3, bl3, Wo, bo, (float*)d_out, G);
}

// Round 2
// 1677.454 us; speedup vs baseline: 6.2666x; 6.2666x over previous
//
#include <hip/hip_runtime.h>
#include <math.h>

#define H 16
#define NF 64
#define TPB 256
#define SBLK 256
#define SITEMS 8   // 2048 elements per scan block; N=150000 -> 74 blocks <= 256 (k_scan2 limit)

__device__ __forceinline__ float lrelu(float v){ return v > 0.f ? v : 0.2f*v; }

// ---- derived edge-attention weights: par[0..1] = We1@ae1, par[2..3] = We2@ae2 ----
__global__ void k_prep(const float* __restrict__ We1, const float* __restrict__ ae1,
                       const float* __restrict__ We2, const float* __restrict__ ae2,
                       float* __restrict__ params){
  int t = threadIdx.x;
  if (t < 4){
    const float* We = (t < 2) ? We1 : We2;
    const float* ae = (t < 2) ? ae1 : ae2;
    int r = t & 1;
    float s = 0.f;
    for (int c = 0; c < H; ++c) s += We[r*H + c] * ae[c];
    params[t] = s;
  }
}

// ---- in-degree histogram (1 int atomic per edge) ----
__global__ __launch_bounds__(TPB) void k_count(const int* __restrict__ dst, int* __restrict__ cnt, int E){
  int e = blockIdx.x*TPB + threadIdx.x;
  if (e >= E) return;
  atomicAdd(&cnt[dst[e]], 1);
}

// ---- exclusive scan of cnt -> rowptr (3 kernels) ----
__global__ __launch_bounds__(SBLK) void k_scan1(const int* __restrict__ cnt, int* __restrict__ part, int N){
  __shared__ int red[SBLK];
  int base = blockIdx.x*SBLK*SITEMS;
  int t = threadIdx.x;
  int s = 0;
  for (int i = 0; i < SITEMS; ++i){
    int idx = base + t*SITEMS + i;
    s += (idx < N) ? cnt[idx] : 0;
  }
  red[t] = s; __syncthreads();
  for (int off = SBLK/2; off > 0; off >>= 1){
    if (t < off) red[t] += red[t+off];
    __syncthreads();
  }
  if (t == 0) part[blockIdx.x] = red[0];
}

__global__ __launch_bounds__(SBLK) void k_scan2(int* __restrict__ part, int nb,
                                                int* __restrict__ rowptr, int N, int E){
  __shared__ int sh[SBLK];
  int t = threadIdx.x;
  int v = (t < nb) ? part[t] : 0;
  sh[t] = v; __syncthreads();
  for (int off = 1; off < SBLK; off <<= 1){
    int add = (t >= off) ? sh[t-off] : 0;
    __syncthreads();
    sh[t] += add;
    __syncthreads();
  }
  if (t < nb) part[t] = sh[t] - v;   // exclusive block offsets
  if (t == 0) rowptr[N] = E;
}

__global__ __launch_bounds__(SBLK) void k_scan3(const int* __restrict__ cnt, const int* __restrict__ part,
                                                int* __restrict__ rowptr, int N){
  __shared__ int sh[SBLK];
  int base = blockIdx.x*SBLK*SITEMS;
  int t = threadIdx.x;
  int loc[SITEMS]; int s = 0;
  for (int i = 0; i < SITEMS; ++i){
    int idx = base + t*SITEMS + i;
    loc[i] = s;
    s += (idx < N) ? cnt[idx] : 0;
  }
  sh[t] = s; __syncthreads();
  for (int off = 1; off < SBLK; off <<= 1){
    int add = (t >= off) ? sh[t-off] : 0;
    __syncthreads();
    sh[t] += add;
    __syncthreads();
  }
  int toff = sh[t] - s + part[blockIdx.x];
  for (int i = 0; i < SITEMS; ++i){
    int idx = base + t*SITEMS + i;
    if (idx < N) rowptr[idx] = toff + loc[i];
  }
}

// ---- CSR fill: csr_src[pos]=src, csr_dot[pos]=(attr.w1, attr.w2) ----
__global__ __launch_bounds__(TPB) void k_fill(const int* __restrict__ src, const int* __restrict__ dst,
    const float* __restrict__ attr, const float* __restrict__ wp, const int* __restrict__ rowptr,
    int* __restrict__ fillc, int* __restrict__ csr_src, float2* __restrict__ csr_dot, int E){
  int e = blockIdx.x*TPB + threadIdx.x;
  if (e >= E) return;
  int d = dst[e];
  float2 a = ((const float2*)attr)[e];
  int pos = rowptr[d] + atomicAdd(&fillc[d], 1);
  csr_src[pos] = src[e];
  csr_dot[pos] = make_float2(a.x*wp[0] + a.y*wp[1], a.x*wp[2] + a.y*wp[3]);
}

// ---- layer-1 node transform: h = x @ W1, alpha_src/dst ----
__global__ __launch_bounds__(TPB) void k_node1(const float* __restrict__ x, const float* __restrict__ W,
    const float* __restrict__ av_s, const float* __restrict__ av_d,
    float* __restrict__ hout, float* __restrict__ asn, float* __restrict__ adn, int N){
  __shared__ float sW[NF*H];
  __shared__ float sas[H], sad[H];
  int t = threadIdx.x;
  for (int i = t; i < NF*H; i += TPB) sW[i] = W[i];
  if (t < H){ sas[t] = av_s[t]; sad[t] = av_d[t]; }
  __syncthreads();
  int n = blockIdx.x*TPB + t;
  if (n >= N) return;
  float h[H];
  #pragma unroll
  for (int j = 0; j < H; ++j) h[j] = 0.f;
  const float4* xr = (const float4*)(x + (size_t)n*NF);
  #pragma unroll
  for (int k4 = 0; k4 < NF/4; ++k4){
    float4 xv = xr[k4];
    #pragma unroll
    for (int j = 0; j < H; ++j){
      h[j] += xv.x*sW[(4*k4+0)*H+j] + xv.y*sW[(4*k4+1)*H+j]
            + xv.z*sW[(4*k4+2)*H+j] + xv.w*sW[(4*k4+3)*H+j];
    }
  }
  float4* ho = (float4*)(hout + (size_t)n*H);
  ho[0] = make_float4(h[0],h[1],h[2],h[3]);
  ho[1] = make_float4(h[4],h[5],h[6],h[7]);
  ho[2] = make_float4(h[8],h[9],h[10],h[11]);
  ho[3] = make_float4(h[12],h[13],h[14],h[15]);
  float ss = 0.f, sd = 0.f;
  #pragma unroll
  for (int j = 0; j < H; ++j){ ss += h[j]*sas[j]; sd += h[j]*sad[j]; }
  asn[n] = ss; adn[n] = sd;
}

// ---- fused GAT aggregation: denom + numerator + self-loop + bias + relu, no atomics ----
// 16 lanes per node (lane j = feature j); h[src] reads are 64B coalesced per group.
__global__ __launch_bounds__(TPB) void k_gat(const int* __restrict__ rowptr,
    const int* __restrict__ csr_src, const float2* __restrict__ csr_dot,
    const float* __restrict__ asn, const float* __restrict__ adn,
    const float* __restrict__ h, const float* __restrict__ bias,
    float* __restrict__ out, int N, int sel){
  int t = threadIdx.x;
  int lane = t & (H-1);
  int n = blockIdx.x*(TPB/H) + (t >> 4);
  if (n >= N) return;
  int r0 = rowptr[n], r1 = rowptr[n+1];
  float adn_n = adn[n];
  float den = 0.f, acc = 0.f, sd = 0.f;
  for (int i = r0; i < r1; ++i){
    int s = csr_src[i];
    float2 dd = csr_dot[i];
    float d = sel ? dd.y : dd.x;
    float w = __expf(lrelu(asn[s] + adn_n + d));
    den += w; sd += d;
    acc += w * h[(size_t)s*H + lane];
  }
  // self-loop: edge_attr = mean of incoming attr -> dot = mean of incoming dots (linear)
  float cntf = (float)(r1 - r0);
  float lael = sd / fmaxf(cntf, 1.f);
  float wl = __expf(lrelu(asn[n] + adn_n + lael));
  den += wl;
  acc += wl * h[(size_t)n*H + lane];
  out[(size_t)n*H + lane] = fmaxf(acc/(den + 1e-16f) + bias[lane], 0.f);
}

// ---- BN sum/sumsq over layer-1 output (read-only, wave-reduced) ----
__global__ __launch_bounds__(TPB) void k_stats(const float* __restrict__ B,
    float* __restrict__ bnstats, int N){
  int t = threadIdx.x;
  int n = blockIdx.x*TPB + t;
  float v[H];
  if (n < N){
    const float4* br = (const float4*)(B + (size_t)n*H);
    float4 a0 = br[0], a1 = br[1], a2 = br[2], a3 = br[3];
    v[0]=a0.x; v[1]=a0.y; v[2]=a0.z; v[3]=a0.w;
    v[4]=a1.x; v[5]=a1.y; v[6]=a1.z; v[7]=a1.w;
    v[8]=a2.x; v[9]=a2.y; v[10]=a2.z; v[11]=a2.w;
    v[12]=a3.x; v[13]=a3.y; v[14]=a3.z; v[15]=a3.w;
  } else {
    #pragma unroll
    for (int f = 0; f < H; ++f) v[f] = 0.f;
  }
  float s[H], q[H];
  #pragma unroll
  for (int f = 0; f < H; ++f){ s[f] = v[f]; q[f] = v[f]*v[f]; }
  for (int m = 1; m < 64; m <<= 1){
    #pragma unroll
    for (int f = 0; f < H; ++f){
      s[f] += __shfl_xor(s[f], m);
      q[f] += __shfl_xor(q[f], m);
    }
  }
  if ((t & 63) == 0){
    #pragma unroll
    for (int f = 0; f < H; ++f){
      atomicAdd(&bnstats[f], s[f]);
      atomicAdd(&bnstats[H+f], q[f]);
    }
  }
}

__global__ void k_bnprep(const float* __restrict__ bnstats, const float* __restrict__ gamma,
    const float* __restrict__ beta, float* __restrict__ scale, float* __restrict__ shift, int N){
  int f = threadIdx.x;
  if (f >= H) return;
  float inv = 1.f / (float)N;
  float mu  = bnstats[f] * inv;
  float var = bnstats[H+f] * inv - mu*mu;
  float sc  = gamma[f] * rsqrtf(var + 1e-5f);
  scale[f] = sc;
  shift[f] = beta[f] - mu*sc;
}

// ---- layer-2 node transform: BN + h = xn @ W2 + alphas ----
__global__ __launch_bounds__(TPB) void k_node2(const float* __restrict__ Bin, const float* __restrict__ scale,
    const float* __restrict__ shift, const float* __restrict__ W,
    const float* __restrict__ av_s, const float* __restrict__ av_d,
    float* __restrict__ hout, float* __restrict__ asn, float* __restrict__ adn, int N){
  __shared__ float sW[H*H];
  __shared__ float ssc[H], ssh[H], sas[H], sad[H];
  int t = threadIdx.x;
  if (t < H*H) sW[t] = W[t];
  if (t < H){ ssc[t] = scale[t]; ssh[t] = shift[t]; sas[t] = av_s[t]; sad[t] = av_d[t]; }
  __syncthreads();
  int n = blockIdx.x*TPB + t;
  if (n >= N) return;
  const float4* br = (const float4*)(Bin + (size_t)n*H);
  float4 a0 = br[0], a1 = br[1], a2 = br[2], a3 = br[3];
  float xn[H] = {a0.x,a0.y,a0.z,a0.w, a1.x,a1.y,a1.z,a1.w,
                 a2.x,a2.y,a2.z,a2.w, a3.x,a3.y,a3.z,a3.w};
  #pragma unroll
  for (int f = 0; f < H; ++f) xn[f] = xn[f]*ssc[f] + ssh[f];
  float h[H];
  #pragma unroll
  for (int j = 0; j < H; ++j) h[j] = 0.f;
  #pragma unroll
  for (int k = 0; k < H; ++k){
    float xv = xn[k];
    #pragma unroll
    for (int j = 0; j < H; ++j) h[j] += xv * sW[k*H+j];
  }
  float4* ho = (float4*)(hout + (size_t)n*H);
  ho[0] = make_float4(h[0],h[1],h[2],h[3]);
  ho[1] = make_float4(h[4],h[5],h[6],h[7]);
  ho[2] = make_float4(h[8],h[9],h[10],h[11]);
  ho[3] = make_float4(h[12],h[13],h[14],h[15]);
  float ss = 0.f, sd = 0.f;
  #pragma unroll
  for (int j = 0; j < H; ++j){ ss += h[j]*sas[j]; sd += h[j]*sad[j]; }
  asn[n] = ss; adn[n] = sd;
}

// ---- mean-pool accumulation; batch is sorted -> wave-uniform fast path ----
__global__ __launch_bounds__(TPB) void k_pool(const float* __restrict__ B,
    const int* __restrict__ batch, float* __restrict__ pooled, float* __restrict__ gcnt, int N){
  int n = blockIdx.x*TPB + threadIdx.x;
  int lane = threadIdx.x & 63;
  bool valid = n < N;
  int g = valid ? batch[n] : -1;
  float v[H];
  if (valid){
    const float4* br = (const float4*)(B + (size_t)n*H);
    float4 a0 = br[0], a1 = br[1], a2 = br[2], a3 = br[3];
    v[0]=a0.x; v[1]=a0.y; v[2]=a0.z; v[3]=a0.w;
    v[4]=a1.x; v[5]=a1.y; v[6]=a1.z; v[7]=a1.w;
    v[8]=a2.x; v[9]=a2.y; v[10]=a2.z; v[11]=a2.w;
    v[12]=a3.x; v[13]=a3.y; v[14]=a3.z; v[15]=a3.w;
  } else {
    #pragma unroll
    for (int f = 0; f < H; ++f) v[f] = 0.f;
  }
  int g0 = __shfl(g, 0);
  bool allsame = __all(valid && g == g0);
  if (allsame){
    float s[H];
    #pragma unroll
    for (int f = 0; f < H; ++f) s[f] = v[f];
    for (int m = 1; m < 64; m <<= 1){
      #pragma unroll
      for (int f = 0; f < H; ++f) s[f] += __shfl_xor(s[f], m);
    }
    if (lane == 0){
      float* p = pooled + (size_t)g0*H;
      #pragma unroll
      for (int f = 0; f < H; ++f) atomicAdd(&p[f], s[f]);
      atomicAdd(&gcnt[g0], 64.f);
    }
  } else if (valid){
    float* p = pooled + (size_t)g*H;
    #pragma unroll
    for (int f = 0; f < H; ++f) atomicAdd(&p[f], v[f]);
    atomicAdd(&gcnt[g], 1.f);
  }
}

// ---- D2RL head: one block of 512 threads (one per graph) ----
__device__ void block_stats16(const float* v, float* mu, float* rs,
                              float* wsum, float* wsq, int G){
  float s[H], q[H];
  #pragma unroll
  for (int f = 0; f < H; ++f){ s[f] = v[f]; q[f] = v[f]*v[f]; }
  for (int m = 1; m < 64; m <<= 1){
    #pragma unroll
    for (int f = 0; f < H; ++f){
      s[f] += __shfl_xor(s[f], m);
      q[f] += __shfl_xor(q[f], m);
    }
  }
  int wave = threadIdx.x >> 6, lane = threadIdx.x & 63;
  if (lane == 0){
    #pragma unroll
    for (int f = 0; f < H; ++f){ wsum[wave*H+f] = s[f]; wsq[wave*H+f] = q[f]; }
  }
  __syncthreads();
  int t = threadIdx.x;
  if (t < H){
    float S = 0.f, Q = 0.f;
    for (int w = 0; w < 8; ++w){ S += wsum[w*H+t]; Q += wsq[w*H+t]; }
    float m_ = S / (float)G;
    float var = Q / (float)G - m_*m_;
    mu[t] = m_;
    rs[t] = rsqrtf(var + 1e-5f);
  }
  __syncthreads();
}

__global__ __launch_bounds__(512) void k_head(const float* __restrict__ pooled, const float* __restrict__ gcnt,
    const float* __restrict__ g1, const float* __restrict__ be1,
    const float* __restrict__ Wl1, const float* __restrict__ bl1,
    const float* __restrict__ g2, const float* __restrict__ be2,
    const float* __restrict__ Wl2, const float* __restrict__ bl2,
    const float* __restrict__ g3, const float* __restrict__ be3,
    const float* __restrict__ Wl3, const float* __restrict__ bl3,
    const float* __restrict__ Wo, const float* __restrict__ bo,
    float* __restrict__ out, int G){
  __shared__ float wsum[8*H], wsq[8*H];
  __shared__ float pmu[H], prs[H], smu[H], srs[H];
  int g = threadIdx.x;
  float p[H];
  if (g < G){
    float c = fmaxf(gcnt[g], 1.f);
    #pragma unroll
    for (int f = 0; f < H; ++f) p[f] = pooled[(size_t)g*H+f] / c;
  } else {
    #pragma unroll
    for (int f = 0; f < H; ++f) p[f] = 0.f;
  }
  block_stats16(p, pmu, prs, wsum, wsq, G);
  float xn[H], z[H];
  #pragma unroll
  for (int f = 0; f < H; ++f) xn[f] = g1[f]*(p[f]-pmu[f])*prs[f] + be1[f];
  #pragma unroll
  for (int j = 0; j < H; ++j) z[j] = bl1[j];
  for (int k = 0; k < H; ++k){
    float xv = xn[k];
    #pragma unroll
    for (int j = 0; j < H; ++j) z[j] += xv * Wl1[k*H+j];
  }
  #pragma unroll
  for (int j = 0; j < H; ++j) z[j] = fmaxf(z[j], 0.f);
  block_stats16(z, smu, srs, wsum, wsq, G);
  float x2[2*H], z2[H];
  #pragma unroll
  for (int f = 0; f < H; ++f){
    x2[f]   = g2[f]  *(z[f]-smu[f])*srs[f] + be2[f];
    x2[H+f] = g2[H+f]*(p[f]-pmu[f])*prs[f] + be2[H+f];
  }
  #pragma unroll
  for (int j = 0; j < H; ++j) z2[j] = bl2[j];
  for (int k = 0; k < 2*H; ++k){
    float xv = x2[k];
    #pragma unroll
    for (int j = 0; j < H; ++j) z2[j] += xv * Wl2[k*H+j];
  }
  #pragma unroll
  for (int j = 0; j < H; ++j) z2[j] = fmaxf(z2[j], 0.f);
  block_stats16(z2, smu, srs, wsum, wsq, G);
  float x3[2*H], z3[H];
  #pragma unroll
  for (int f = 0; f < H; ++f){
    x3[f]   = g3[f]  *(z2[f]-smu[f])*srs[f] + be3[f];
    x3[H+f] = g3[H+f]*(p[f]-pmu[f])*prs[f] + be3[H+f];
  }
  #pragma unroll
  for (int j = 0; j < H; ++j) z3[j] = bl3[j];
  for (int k = 0; k < 2*H; ++k){
    float xv = x3[k];
    #pragma unroll
    for (int j = 0; j < H; ++j) z3[j] += xv * Wl3[k*H+j];
  }
  #pragma unroll
  for (int j = 0; j < H; ++j) z3[j] = fmaxf(z3[j], 0.f);
  if (g < G){
    float o = bo[0];
    #pragma unroll
    for (int j = 0; j < H; ++j) o += z3[j]*Wo[j];
    out[g] = o;
  }
}

extern "C" void kernel_launch(void* const* d_in, const int* in_sizes, int n_in,
                              void* d_out, int out_size, void* d_ws, size_t ws_size,
                              hipStream_t stream) {
  const float* x     = (const float*)d_in[0];
  const int*   ei    = (const int*)d_in[1];
  const float* attr  = (const float*)d_in[2];
  const int*   batch = (const int*)d_in[3];
  const float* W1  = (const float*)d_in[4];
  const float* We1 = (const float*)d_in[5];
  const float* as1 = (const float*)d_in[6];
  const float* ad1 = (const float*)d_in[7];
  const float* ae1 = (const float*)d_in[8];
  const float* b1  = (const float*)d_in[9];
  const float* bn1g = (const float*)d_in[10];
  const float* bn1b = (const float*)d_in[11];
  const float* W2  = (const float*)d_in[12];
  const float* We2 = (const float*)d_in[13];
  const float* as2 = (const float*)d_in[14];
  const float* ad2 = (const float*)d_in[15];
  const float* ae2 = (const float*)d_in[16];
  const float* b2  = (const float*)d_in[17];
  const float* bnl1g = (const float*)d_in[18];
  const float* bnl1b = (const float*)d_in[19];
  const float* Wl1 = (const float*)d_in[20];
  const float* bl1 = (const float*)d_in[21];
  const float* bnl2g = (const float*)d_in[22];
  const float* bnl2b = (const float*)d_in[23];
  const float* Wl2 = (const float*)d_in[24];
  const float* bl2 = (const float*)d_in[25];
  const float* bnl3g = (const float*)d_in[26];
  const float* bnl3b = (const float*)d_in[27];
  const float* Wl3 = (const float*)d_in[28];
  const float* bl3 = (const float*)d_in[29];
  const float* Wo  = (const float*)d_in[30];
  const float* bo  = (const float*)d_in[31];

  int N = in_sizes[0] / NF;
  int E = in_sizes[1] / 2;
  int G = out_size;
  const int* srcp = ei;
  const int* dstp = ei + E;

  // ---- workspace layout (units of 4 bytes) ----
  char* wsb = (char*)d_ws;
  size_t off = 0;
  auto alloc = [&](size_t elems4) { void* p = wsb + off*4; off += elems4; return p; };
  float* A      = (float*)alloc((size_t)16*N);       // h (current layer)
  float* Bv     = (float*)alloc((size_t)16*N);       // layer output
  float* asn    = (float*)alloc(N);
  float* adn    = (float*)alloc(N);
  int*   cntI   = (int*)  alloc(N);                  // in-degree (zeroed)
  int*   rowptr = (int*)  alloc(N+1);
  int*   fillc  = (int*)  alloc(N);                  // fill cursors (zeroed)
  int*   part   = (int*)  alloc(256);
  float* par    = (float*)alloc(128);                // [0..3]=wp [4..35]=bnstats [36..51]=scale [52..67]=shift
  float* pooled = (float*)alloc((size_t)G*H);
  float* gcnt   = (float*)alloc(G);
  if (off & 1) off++;                                // 8B-align csr_dot
  float2* csr_dot = (float2*)alloc((size_t)2*E);
  int*    csr_src = (int*)  alloc(E);

  float* bnstats = par + 4;
  float* bnscale = par + 36;
  float* bnshift = par + 52;

  int nbE  = (E + TPB - 1)/TPB;
  int nbN  = (N + TPB - 1)/TPB;
  int nbS  = (N + SBLK*SITEMS - 1)/(SBLK*SITEMS);    // scan blocks (74 for N=150000)
  int nbG  = (N + (TPB/H) - 1)/(TPB/H);              // k_gat blocks (16 nodes/block)

  // zero-init (ws is re-poisoned 0xAA before every launch)
  hipMemsetAsync(cntI, 0, (size_t)N*sizeof(int), stream);
  hipMemsetAsync(fillc, 0, (size_t)N*sizeof(int), stream);
  hipMemsetAsync(bnstats, 0, 32*sizeof(float), stream);
  hipMemsetAsync(pooled, 0, (size_t)(G*H + G)*sizeof(float), stream);

  k_prep<<<1, 64, 0, stream>>>(We1, ae1, We2, ae2, par);

  // ---- CSR build ----
  k_count<<<nbE, TPB, 0, stream>>>(dstp, cntI, E);
  k_scan1<<<nbS, SBLK, 0, stream>>>(cntI, part, N);
  k_scan2<<<1, SBLK, 0, stream>>>(part, nbS, rowptr, N, E);
  k_scan3<<<nbS, SBLK, 0, stream>>>(cntI, part, rowptr, N);
  k_fill<<<nbE, TPB, 0, stream>>>(srcp, dstp, attr, par, rowptr, fillc, csr_src, csr_dot, E);

  // ---- layer 1 ----
  k_node1<<<nbN, TPB, 0, stream>>>(x, W1, as1, ad1, A, asn, adn, N);
  k_gat<<<nbG, TPB, 0, stream>>>(rowptr, csr_src, csr_dot, asn, adn, A, b1, Bv, N, 0);
  k_stats<<<nbN, TPB, 0, stream>>>(Bv, bnstats, N);
  k_bnprep<<<1, 64, 0, stream>>>(bnstats, bn1g, bn1b, bnscale, bnshift, N);

  // ---- layer 2 ----
  k_node2<<<nbN, TPB, 0, stream>>>(Bv, bnscale, bnshift, W2, as2, ad2, A, asn, adn, N);
  k_gat<<<nbG, TPB, 0, stream>>>(rowptr, csr_src, csr_dot, asn, adn, A, b2, Bv, N, 1);

  // ---- pool + head ----
  k_pool<<<nbN, TPB, 0, stream>>>(Bv, batch, pooled, gcnt, N);
  k_head<<<1, 512, 0, stream>>>(pooled, gcnt, bnl1g, bnl1b, Wl1, bl1, bnl2g, bnl2b, Wl2, bl2,
                                bnl3g, bnl3b, Wl3, bl3, Wo, bo, (float*)d_out, G);
}

// Round 3
// 1070.140 us; speedup vs baseline: 9.8230x; 1.5675x over previous
//
#include <hip/hip_runtime.h>
#include <math.h>

#define H 16
#define NF 64
#define TPB 256
#define SBLK 256
#define SITEMS 8   // 2048 elements per scan block; N=150000 -> 74 blocks <= 256 (k_scan2 limit)

__device__ __forceinline__ float lrelu(float v){ return v > 0.f ? v : 0.2f*v; }

// ---- derived edge-attention weights: par[0..1] = We1@ae1, par[2..3] = We2@ae2 ----
__global__ void k_prep(const float* __restrict__ We1, const float* __restrict__ ae1,
                       const float* __restrict__ We2, const float* __restrict__ ae2,
                       float* __restrict__ params){
  int t = threadIdx.x;
  if (t < 4){
    const float* We = (t < 2) ? We1 : We2;
    const float* ae = (t < 2) ? ae1 : ae2;
    int r = t & 1;
    float s = 0.f;
    for (int c = 0; c < H; ++c) s += We[r*H + c] * ae[c];
    params[t] = s;
  }
}

// ---- in-degree histogram (1 int atomic per edge) ----
__global__ __launch_bounds__(TPB) void k_count(const int* __restrict__ dst, int* __restrict__ cnt, int E){
  int e = blockIdx.x*TPB + threadIdx.x;
  if (e >= E) return;
  atomicAdd(&cnt[dst[e]], 1);
}

// ---- exclusive scan of cnt -> rowptr (3 kernels) ----
__global__ __launch_bounds__(SBLK) void k_scan1(const int* __restrict__ cnt, int* __restrict__ part, int N){
  __shared__ int red[SBLK];
  int base = blockIdx.x*SBLK*SITEMS;
  int t = threadIdx.x;
  int s = 0;
  for (int i = 0; i < SITEMS; ++i){
    int idx = base + t*SITEMS + i;
    s += (idx < N) ? cnt[idx] : 0;
  }
  red[t] = s; __syncthreads();
  for (int off = SBLK/2; off > 0; off >>= 1){
    if (t < off) red[t] += red[t+off];
    __syncthreads();
  }
  if (t == 0) part[blockIdx.x] = red[0];
}

__global__ __launch_bounds__(SBLK) void k_scan2(int* __restrict__ part, int nb,
                                                int* __restrict__ rowptr, int N, int E){
  __shared__ int sh[SBLK];
  int t = threadIdx.x;
  int v = (t < nb) ? part[t] : 0;
  sh[t] = v; __syncthreads();
  for (int off = 1; off < SBLK; off <<= 1){
    int add = (t >= off) ? sh[t-off] : 0;
    __syncthreads();
    sh[t] += add;
    __syncthreads();
  }
  if (t < nb) part[t] = sh[t] - v;   // exclusive block offsets
  if (t == 0) rowptr[N] = E;
}

__global__ __launch_bounds__(SBLK) void k_scan3(const int* __restrict__ cnt, const int* __restrict__ part,
                                                int* __restrict__ rowptr, int N){
  __shared__ int sh[SBLK];
  int base = blockIdx.x*SBLK*SITEMS;
  int t = threadIdx.x;
  int loc[SITEMS]; int s = 0;
  for (int i = 0; i < SITEMS; ++i){
    int idx = base + t*SITEMS + i;
    loc[i] = s;
    s += (idx < N) ? cnt[idx] : 0;
  }
  sh[t] = s; __syncthreads();
  for (int off = 1; off < SBLK; off <<= 1){
    int add = (t >= off) ? sh[t-off] : 0;
    __syncthreads();
    sh[t] += add;
    __syncthreads();
  }
  int toff = sh[t] - s + part[blockIdx.x];
  for (int i = 0; i < SITEMS; ++i){
    int idx = base + t*SITEMS + i;
    if (idx < N) rowptr[idx] = toff + loc[i];
  }
}

// ---- CSR fill: csr_src[pos]=src, csr_dot[pos]=(attr.w1, attr.w2) ----
__global__ __launch_bounds__(TPB) void k_fill(const int* __restrict__ src, const int* __restrict__ dst,
    const float* __restrict__ attr, const float* __restrict__ wp, const int* __restrict__ rowptr,
    int* __restrict__ fillc, int* __restrict__ csr_src, float2* __restrict__ csr_dot, int E){
  int e = blockIdx.x*TPB + threadIdx.x;
  if (e >= E) return;
  int d = dst[e];
  float2 a = ((const float2*)attr)[e];
  int pos = rowptr[d] + atomicAdd(&fillc[d], 1);
  csr_src[pos] = src[e];
  csr_dot[pos] = make_float2(a.x*wp[0] + a.y*wp[1], a.x*wp[2] + a.y*wp[3]);
}

// ---- layer-1 node transform: h = x @ W1, alpha_src/dst ----
__global__ __launch_bounds__(TPB) void k_node1(const float* __restrict__ x, const float* __restrict__ W,
    const float* __restrict__ av_s, const float* __restrict__ av_d,
    float* __restrict__ hout, float* __restrict__ asn, float* __restrict__ adn, int N){
  __shared__ float sW[NF*H];
  __shared__ float sas[H], sad[H];
  int t = threadIdx.x;
  for (int i = t; i < NF*H; i += TPB) sW[i] = W[i];
  if (t < H){ sas[t] = av_s[t]; sad[t] = av_d[t]; }
  __syncthreads();
  int n = blockIdx.x*TPB + t;
  if (n >= N) return;
  float h[H];
  #pragma unroll
  for (int j = 0; j < H; ++j) h[j] = 0.f;
  const float4* xr = (const float4*)(x + (size_t)n*NF);
  #pragma unroll
  for (int k4 = 0; k4 < NF/4; ++k4){
    float4 xv = xr[k4];
    #pragma unroll
    for (int j = 0; j < H; ++j){
      h[j] += xv.x*sW[(4*k4+0)*H+j] + xv.y*sW[(4*k4+1)*H+j]
            + xv.z*sW[(4*k4+2)*H+j] + xv.w*sW[(4*k4+3)*H+j];
    }
  }
  float4* ho = (float4*)(hout + (size_t)n*H);
  ho[0] = make_float4(h[0],h[1],h[2],h[3]);
  ho[1] = make_float4(h[4],h[5],h[6],h[7]);
  ho[2] = make_float4(h[8],h[9],h[10],h[11]);
  ho[3] = make_float4(h[12],h[13],h[14],h[15]);
  float ss = 0.f, sd = 0.f;
  #pragma unroll
  for (int j = 0; j < H; ++j){ ss += h[j]*sas[j]; sd += h[j]*sad[j]; }
  asn[n] = ss; adn[n] = sd;
}

// ---- fused GAT aggregation: denom + numerator + self-loop + bias + relu, no atomics ----
// 16 lanes per node (lane j = feature j); unroll-by-4 keeps 4 independent
// src/asn/h-row gathers in flight (the serial dependent chain was the stall).
template<int SEL>
__global__ __launch_bounds__(TPB) void k_gat(const int* __restrict__ rowptr,
    const int* __restrict__ csr_src, const float2* __restrict__ csr_dot,
    const float* __restrict__ asn, const float* __restrict__ adn,
    const float* __restrict__ h, const float* __restrict__ bias,
    float* __restrict__ out, int N){
  int t = threadIdx.x;
  int lane = t & (H-1);
  int n = blockIdx.x*(TPB/H) + (t >> 4);
  if (n >= N) return;
  int r0 = rowptr[n], r1 = rowptr[n+1];
  float adn_n = adn[n];
  float den = 0.f, acc = 0.f, sd = 0.f;
  int i = r0;
  for (; i + 4 <= r1; i += 4){
    int s0 = csr_src[i+0], s1 = csr_src[i+1], s2 = csr_src[i+2], s3 = csr_src[i+3];
    float2 e0 = csr_dot[i+0], e1 = csr_dot[i+1], e2 = csr_dot[i+2], e3 = csr_dot[i+3];
    float a0 = asn[s0], a1 = asn[s1], a2 = asn[s2], a3 = asn[s3];
    float h0 = h[(size_t)s0*H+lane], h1 = h[(size_t)s1*H+lane],
          h2 = h[(size_t)s2*H+lane], h3 = h[(size_t)s3*H+lane];
    float d0 = SEL ? e0.y : e0.x, d1 = SEL ? e1.y : e1.x,
          d2 = SEL ? e2.y : e2.x, d3 = SEL ? e3.y : e3.x;
    float w0 = __expf(lrelu(a0 + adn_n + d0));
    float w1 = __expf(lrelu(a1 + adn_n + d1));
    float w2 = __expf(lrelu(a2 + adn_n + d2));
    float w3 = __expf(lrelu(a3 + adn_n + d3));
    den += (w0 + w1) + (w2 + w3);
    sd  += (d0 + d1) + (d2 + d3);
    acc += (w0*h0 + w1*h1) + (w2*h2 + w3*h3);
  }
  for (; i < r1; ++i){
    int s = csr_src[i];
    float2 e = csr_dot[i];
    float d = SEL ? e.y : e.x;
    float w = __expf(lrelu(asn[s] + adn_n + d));
    den += w; sd += d;
    acc += w * h[(size_t)s*H + lane];
  }
  // self-loop: edge_attr = mean of incoming attr -> dot = mean of incoming dots (linear)
  float cntf = (float)(r1 - r0);
  float lael = sd / fmaxf(cntf, 1.f);
  float wl = __expf(lrelu(asn[n] + adn_n + lael));
  den += wl;
  acc += wl * h[(size_t)n*H + lane];
  out[(size_t)n*H + lane] = fmaxf(acc/(den + 1e-16f) + bias[lane], 0.f);
}

// ---- BN sum/sumsq: per-block partials, ZERO global atomics ----
// (round-2 k_stats spent 488us on 75K same-line global f32 atomics)
__global__ __launch_bounds__(TPB) void k_stats(const float* __restrict__ B,
    float* __restrict__ partial, int N){
  __shared__ float lds[4][32];
  int t = threadIdx.x;
  int n = blockIdx.x*TPB + t;
  float v[H];
  if (n < N){
    const float4* br = (const float4*)(B + (size_t)n*H);
    float4 a0 = br[0], a1 = br[1], a2 = br[2], a3 = br[3];
    v[0]=a0.x; v[1]=a0.y; v[2]=a0.z; v[3]=a0.w;
    v[4]=a1.x; v[5]=a1.y; v[6]=a1.z; v[7]=a1.w;
    v[8]=a2.x; v[9]=a2.y; v[10]=a2.z; v[11]=a2.w;
    v[12]=a3.x; v[13]=a3.y; v[14]=a3.z; v[15]=a3.w;
  } else {
    #pragma unroll
    for (int f = 0; f < H; ++f) v[f] = 0.f;
  }
  float s[H], q[H];
  #pragma unroll
  for (int f = 0; f < H; ++f){ s[f] = v[f]; q[f] = v[f]*v[f]; }
  for (int m = 1; m < 64; m <<= 1){
    #pragma unroll
    for (int f = 0; f < H; ++f){
      s[f] += __shfl_xor(s[f], m);
      q[f] += __shfl_xor(q[f], m);
    }
  }
  int wave = t >> 6, lane = t & 63;
  if (lane == 0){
    #pragma unroll
    for (int f = 0; f < H; ++f){ lds[wave][f] = s[f]; lds[wave][H+f] = q[f]; }
  }
  __syncthreads();
  if (t < 32)
    partial[(size_t)blockIdx.x*32 + t] = lds[0][t] + lds[1][t] + lds[2][t] + lds[3][t];
}

// ---- final BN reduction over block partials + scale/shift ----
__global__ __launch_bounds__(256) void k_bnprep(const float* __restrict__ partial, int nb,
    const float* __restrict__ gamma, const float* __restrict__ beta,
    float* __restrict__ scale, float* __restrict__ shift, int N){
  __shared__ float red[256];
  __shared__ float tot[32];
  int t = threadIdx.x;
  int f = t & 31, c = t >> 5;        // 8 chunks x 32 features
  float s = 0.f;
  for (int b = c; b < nb; b += 8) s += partial[(size_t)b*32 + f];
  red[c*32 + f] = s;
  __syncthreads();
  if (t < 32){
    float S = 0.f;
    #pragma unroll
    for (int cc = 0; cc < 8; ++cc) S += red[cc*32 + t];
    tot[t] = S;
  }
  __syncthreads();
  if (t < H){
    float inv = 1.f / (float)N;
    float mu  = tot[t] * inv;
    float var = tot[H+t] * inv - mu*mu;
    float sc  = gamma[t] * rsqrtf(var + 1e-5f);
    scale[t] = sc;
    shift[t] = beta[t] - mu*sc;
  }
}

// ---- layer-2 node transform: BN + h = xn @ W2 + alphas ----
__global__ __launch_bounds__(TPB) void k_node2(const float* __restrict__ Bin, const float* __restrict__ scale,
    const float* __restrict__ shift, const float* __restrict__ W,
    const float* __restrict__ av_s, const float* __restrict__ av_d,
    float* __restrict__ hout, float* __restrict__ asn, float* __restrict__ adn, int N){
  __shared__ float sW[H*H];
  __shared__ float ssc[H], ssh[H], sas[H], sad[H];
  int t = threadIdx.x;
  if (t < H*H) sW[t] = W[t];
  if (t < H){ ssc[t] = scale[t]; ssh[t] = shift[t]; sas[t] = av_s[t]; sad[t] = av_d[t]; }
  __syncthreads();
  int n = blockIdx.x*TPB + t;
  if (n >= N) return;
  const float4* br = (const float4*)(Bin + (size_t)n*H);
  float4 a0 = br[0], a1 = br[1], a2 = br[2], a3 = br[3];
  float xn[H] = {a0.x,a0.y,a0.z,a0.w, a1.x,a1.y,a1.z,a1.w,
                 a2.x,a2.y,a2.z,a2.w, a3.x,a3.y,a3.z,a3.w};
  #pragma unroll
  for (int f = 0; f < H; ++f) xn[f] = xn[f]*ssc[f] + ssh[f];
  float h[H];
  #pragma unroll
  for (int j = 0; j < H; ++j) h[j] = 0.f;
  #pragma unroll
  for (int k = 0; k < H; ++k){
    float xv = xn[k];
    #pragma unroll
    for (int j = 0; j < H; ++j) h[j] += xv * sW[k*H+j];
  }
  float4* ho = (float4*)(hout + (size_t)n*H);
  ho[0] = make_float4(h[0],h[1],h[2],h[3]);
  ho[1] = make_float4(h[4],h[5],h[6],h[7]);
  ho[2] = make_float4(h[8],h[9],h[10],h[11]);
  ho[3] = make_float4(h[12],h[13],h[14],h[15]);
  float ss = 0.f, sd = 0.f;
  #pragma unroll
  for (int j = 0; j < H; ++j){ ss += h[j]*sas[j]; sd += h[j]*sad[j]; }
  asn[n] = ss; adn[n] = sd;
}

// ---- mean-pool accumulation; batch is sorted -> wave-uniform fast path ----
__global__ __launch_bounds__(TPB) void k_pool(const float* __restrict__ B,
    const int* __restrict__ batch, float* __restrict__ pooled, float* __restrict__ gcnt, int N){
  int n = blockIdx.x*TPB + threadIdx.x;
  int lane = threadIdx.x & 63;
  bool valid = n < N;
  int g = valid ? batch[n] : -1;
  float v[H];
  if (valid){
    const float4* br = (const float4*)(B + (size_t)n*H);
    float4 a0 = br[0], a1 = br[1], a2 = br[2], a3 = br[3];
    v[0]=a0.x; v[1]=a0.y; v[2]=a0.z; v[3]=a0.w;
    v[4]=a1.x; v[5]=a1.y; v[6]=a1.z; v[7]=a1.w;
    v[8]=a2.x; v[9]=a2.y; v[10]=a2.z; v[11]=a2.w;
    v[12]=a3.x; v[13]=a3.y; v[14]=a3.z; v[15]=a3.w;
  } else {
    #pragma unroll
    for (int f = 0; f < H; ++f) v[f] = 0.f;
  }
  int g0 = __shfl(g, 0);
  bool allsame = __all(valid && g == g0);
  if (allsame){
    float s[H];
    #pragma unroll
    for (int f = 0; f < H; ++f) s[f] = v[f];
    for (int m = 1; m < 64; m <<= 1){
      #pragma unroll
      for (int f = 0; f < H; ++f) s[f] += __shfl_xor(s[f], m);
    }
    if (lane == 0){
      float* p = pooled + (size_t)g0*H;
      #pragma unroll
      for (int f = 0; f < H; ++f) atomicAdd(&p[f], s[f]);
      atomicAdd(&gcnt[g0], 64.f);
    }
  } else if (valid){
    float* p = pooled + (size_t)g*H;
    #pragma unroll
    for (int f = 0; f < H; ++f) atomicAdd(&p[f], v[f]);
    atomicAdd(&gcnt[g], 1.f);
  }
}

// ---- D2RL head: one block of 512 threads (one per graph) ----
__device__ void block_stats16(const float* v, float* mu, float* rs,
                              float* wsum, float* wsq, int G){
  float s[H], q[H];
  #pragma unroll
  for (int f = 0; f < H; ++f){ s[f] = v[f]; q[f] = v[f]*v[f]; }
  for (int m = 1; m < 64; m <<= 1){
    #pragma unroll
    for (int f = 0; f < H; ++f){
      s[f] += __shfl_xor(s[f], m);
      q[f] += __shfl_xor(q[f], m);
    }
  }
  int wave = threadIdx.x >> 6, lane = threadIdx.x & 63;
  if (lane == 0){
    #pragma unroll
    for (int f = 0; f < H; ++f){ wsum[wave*H+f] = s[f]; wsq[wave*H+f] = q[f]; }
  }
  __syncthreads();
  int t = threadIdx.x;
  if (t < H){
    float S = 0.f, Q = 0.f;
    for (int w = 0; w < 8; ++w){ S += wsum[w*H+t]; Q += wsq[w*H+t]; }
    float m_ = S / (float)G;
    float var = Q / (float)G - m_*m_;
    mu[t] = m_;
    rs[t] = rsqrtf(var + 1e-5f);
  }
  __syncthreads();
}

__global__ __launch_bounds__(512) void k_head(const float* __restrict__ pooled, const float* __restrict__ gcnt,
    const float* __restrict__ g1, const float* __restrict__ be1,
    const float* __restrict__ Wl1, const float* __restrict__ bl1,
    const float* __restrict__ g2, const float* __restrict__ be2,
    const float* __restrict__ Wl2, const float* __restrict__ bl2,
    const float* __restrict__ g3, const float* __restrict__ be3,
    const float* __restrict__ Wl3, const float* __restrict__ bl3,
    const float* __restrict__ Wo, const float* __restrict__ bo,
    float* __restrict__ out, int G){
  __shared__ float wsum[8*H], wsq[8*H];
  __shared__ float pmu[H], prs[H], smu[H], srs[H];
  int g = threadIdx.x;
  float p[H];
  if (g < G){
    float c = fmaxf(gcnt[g], 1.f);
    #pragma unroll
    for (int f = 0; f < H; ++f) p[f] = pooled[(size_t)g*H+f] / c;
  } else {
    #pragma unroll
    for (int f = 0; f < H; ++f) p[f] = 0.f;
  }
  block_stats16(p, pmu, prs, wsum, wsq, G);
  float xn[H], z[H];
  #pragma unroll
  for (int f = 0; f < H; ++f) xn[f] = g1[f]*(p[f]-pmu[f])*prs[f] + be1[f];
  #pragma unroll
  for (int j = 0; j < H; ++j) z[j] = bl1[j];
  for (int k = 0; k < H; ++k){
    float xv = xn[k];
    #pragma unroll
    for (int j = 0; j < H; ++j) z[j] += xv * Wl1[k*H+j];
  }
  #pragma unroll
  for (int j = 0; j < H; ++j) z[j] = fmaxf(z[j], 0.f);
  block_stats16(z, smu, srs, wsum, wsq, G);
  float x2[2*H], z2[H];
  #pragma unroll
  for (int f = 0; f < H; ++f){
    x2[f]   = g2[f]  *(z[f]-smu[f])*srs[f] + be2[f];
    x2[H+f] = g2[H+f]*(p[f]-pmu[f])*prs[f] + be2[H+f];
  }
  #pragma unroll
  for (int j = 0; j < H; ++j) z2[j] = bl2[j];
  for (int k = 0; k < 2*H; ++k){
    float xv = x2[k];
    #pragma unroll
    for (int j = 0; j < H; ++j) z2[j] += xv * Wl2[k*H+j];
  }
  #pragma unroll
  for (int j = 0; j < H; ++j) z2[j] = fmaxf(z2[j], 0.f);
  block_stats16(z2, smu, srs, wsum, wsq, G);
  float x3[2*H], z3[H];
  #pragma unroll
  for (int f = 0; f < H; ++f){
    x3[f]   = g3[f]  *(z2[f]-smu[f])*srs[f] + be3[f];
    x3[H+f] = g3[H+f]*(p[f]-pmu[f])*prs[f] + be3[H+f];
  }
  #pragma unroll
  for (int j = 0; j < H; ++j) z3[j] = bl3[j];
  for (int k = 0; k < 2*H; ++k){
    float xv = x3[k];
    #pragma unroll
    for (int j = 0; j < H; ++j) z3[j] += xv * Wl3[k*H+j];
  }
  #pragma unroll
  for (int j = 0; j < H; ++j) z3[j] = fmaxf(z3[j], 0.f);
  if (g < G){
    float o = bo[0];
    #pragma unroll
    for (int j = 0; j < H; ++j) o += z3[j]*Wo[j];
    out[g] = o;
  }
}

extern "C" void kernel_launch(void* const* d_in, const int* in_sizes, int n_in,
                              void* d_out, int out_size, void* d_ws, size_t ws_size,
                              hipStream_t stream) {
  const float* x     = (const float*)d_in[0];
  const int*   ei    = (const int*)d_in[1];
  const float* attr  = (const float*)d_in[2];
  const int*   batch = (const int*)d_in[3];
  const float* W1  = (const float*)d_in[4];
  const float* We1 = (const float*)d_in[5];
  const float* as1 = (const float*)d_in[6];
  const float* ad1 = (const float*)d_in[7];
  const float* ae1 = (const float*)d_in[8];
  const float* b1  = (const float*)d_in[9];
  const float* bn1g = (const float*)d_in[10];
  const float* bn1b = (const float*)d_in[11];
  const float* W2  = (const float*)d_in[12];
  const float* We2 = (const float*)d_in[13];
  const float* as2 = (const float*)d_in[14];
  const float* ad2 = (const float*)d_in[15];
  const float* ae2 = (const float*)d_in[16];
  const float* b2  = (const float*)d_in[17];
  const float* bnl1g = (const float*)d_in[18];
  const float* bnl1b = (const float*)d_in[19];
  const float* Wl1 = (const float*)d_in[20];
  const float* bl1 = (const float*)d_in[21];
  const float* bnl2g = (const float*)d_in[22];
  const float* bnl2b = (const float*)d_in[23];
  const float* Wl2 = (const float*)d_in[24];
  const float* bl2 = (const float*)d_in[25];
  const float* bnl3g = (const float*)d_in[26];
  const float* bnl3b = (const float*)d_in[27];
  const float* Wl3 = (const float*)d_in[28];
  const float* bl3 = (const float*)d_in[29];
  const float* Wo  = (const float*)d_in[30];
  const float* bo  = (const float*)d_in[31];

  int N = in_sizes[0] / NF;
  int E = in_sizes[1] / 2;
  int G = out_size;
  const int* srcp = ei;
  const int* dstp = ei + E;

  int nbE  = (E + TPB - 1)/TPB;
  int nbN  = (N + TPB - 1)/TPB;
  int nbS  = (N + SBLK*SITEMS - 1)/(SBLK*SITEMS);    // scan blocks (74 for N=150000)
  int nbG  = (N + (TPB/H) - 1)/(TPB/H);              // k_gat blocks (16 nodes/block)

  // ---- workspace layout (units of 4 bytes) ----
  char* wsb = (char*)d_ws;
  size_t off = 0;
  auto alloc = [&](size_t elems4) { void* p = wsb + off*4; off += elems4; return p; };
  float* A      = (float*)alloc((size_t)16*N);       // h (current layer)
  float* Bv     = (float*)alloc((size_t)16*N);       // layer output
  float* asn    = (float*)alloc(N);
  float* adn    = (float*)alloc(N);
  int*   cntI   = (int*)  alloc(N);                  // in-degree (zeroed)
  int*   rowptr = (int*)  alloc(N+1);
  int*   fillc  = (int*)  alloc(N);                  // fill cursors (zeroed)
  int*   part   = (int*)  alloc(256);
  float* par    = (float*)alloc(64);                 // [0..3]=wp [4..19]=scale [20..35]=shift
  float* pooled = (float*)alloc((size_t)G*H);
  float* gcnt   = (float*)alloc(G);
  float* partial= (float*)alloc((size_t)nbN*32);     // BN per-block partials
  if (off & 1) off++;                                // 8B-align csr_dot
  float2* csr_dot = (float2*)alloc((size_t)2*E);
  int*    csr_src = (int*)  alloc(E);

  float* bnscale = par + 4;
  float* bnshift = par + 20;

  // zero-init (ws is re-poisoned 0xAA before every launch)
  hipMemsetAsync(cntI, 0, (size_t)N*sizeof(int), stream);
  hipMemsetAsync(fillc, 0, (size_t)N*sizeof(int), stream);
  hipMemsetAsync(pooled, 0, (size_t)(G*H + G)*sizeof(float), stream);

  k_prep<<<1, 64, 0, stream>>>(We1, ae1, We2, ae2, par);

  // ---- CSR build ----
  k_count<<<nbE, TPB, 0, stream>>>(dstp, cntI, E);
  k_scan1<<<nbS, SBLK, 0, stream>>>(cntI, part, N);
  k_scan2<<<1, SBLK, 0, stream>>>(part, nbS, rowptr, N, E);
  k_scan3<<<nbS, SBLK, 0, stream>>>(cntI, part, rowptr, N);
  k_fill<<<nbE, TPB, 0, stream>>>(srcp, dstp, attr, par, rowptr, fillc, csr_src, csr_dot, E);

  // ---- layer 1 ----
  k_node1<<<nbN, TPB, 0, stream>>>(x, W1, as1, ad1, A, asn, adn, N);
  k_gat<0><<<nbG, TPB, 0, stream>>>(rowptr, csr_src, csr_dot, asn, adn, A, b1, Bv, N);
  k_stats<<<nbN, TPB, 0, stream>>>(Bv, partial, N);
  k_bnprep<<<1, 256, 0, stream>>>(partial, nbN, bn1g, bn1b, bnscale, bnshift, N);

  // ---- layer 2 ----
  k_node2<<<nbN, TPB, 0, stream>>>(Bv, bnscale, bnshift, W2, as2, ad2, A, asn, adn, N);
  k_gat<1><<<nbG, TPB, 0, stream>>>(rowptr, csr_src, csr_dot, asn, adn, A, b2, Bv, N);

  // ---- pool + head ----
  k_pool<<<nbN, TPB, 0, stream>>>(Bv, batch, pooled, gcnt, N);
  k_head<<<1, 512, 0, stream>>>(pooled, gcnt, bnl1g, bnl1b, Wl1, bl1, bnl2g, bnl2b, Wl2, bl2,
                                bnl3g, bnl3b, Wl3, bl3, Wo, bo, (float*)d_out, G);
}